// Round 13
// baseline (73.892 us; speedup 1.0000x reference)
//
#include <hip/hip_runtime.h>
#include <hip/hip_bf16.h>

// ScatterHorizontal round 13: single-dispatch fused (R12) + B-fragment
// PREFETCH one iteration ahead (fixes R12's regression: wts loads were on the
// per-iter critical path; now issued at iter i for iter i+1 and converted
// after the barrier, consumed wait-free next iter — same discipline as the
// x-staging). biasEff computed per-block into LDS. R6 body otherwise.
// out[b,o,h,w'] = sum_i [0<=w'-d_i<9]( sum_c W[i,o,c]*x_i[b,c,h,w'-d_i] + bias[i,o] )

#define CIN   64
#define COUT  64
#define NOFF  9
#define HW    81
#define SLAB  5184           // f32 per (b,i) slab
#define RSTB  136            // LDS row stride bytes (64 bf16 = 128 + 8 pad)
#define ZR    81             // zero row index
#define BUFB  (82 * RSTB)    // 11152 B per buffer (rows 0..80 data, row 81 zero)

typedef short bf16x8 __attribute__((ext_vector_type(8)));
typedef float f32x4  __attribute__((ext_vector_type(4)));

static __device__ __forceinline__ unsigned int f2bf(float v) {
    union { __hip_bfloat16 h; unsigned short u; } cv;
    cv.h = __float2bfloat16(v);
    return (unsigned int)cv.u;
}

__global__ __launch_bounds__(256, 4) void scatter_fused2_kernel(
    const float* __restrict__ x0, const float* __restrict__ x1,
    const float* __restrict__ x2, const float* __restrict__ x3,
    const float* __restrict__ x4, const float* __restrict__ x5,
    const float* __restrict__ x6, const float* __restrict__ x7,
    const float* __restrict__ x8,
    const float* __restrict__ wts,    // [9][64][64] (i,o,c) f32
    const float* __restrict__ bias,   // [9][64] f32
    float* __restrict__ out)
{
    __shared__ __align__(16) unsigned char xs[2 * BUFB];   // 22304 B
    __shared__ float beff[9 * COUT];                       // 2304 B

    const int b    = blockIdx.x;
    const int t    = threadIdx.x;
    const int wid  = t >> 6;
    const int lane = t & 63;
    const int l15  = lane & 15;
    const int lhi  = lane >> 4;      // 0..3
    const int mh   = wid >> 1;       // m-half: rows mh*48 + [0,48)
    const int oh   = wid & 1;        // o-half: cols oh*32 + [0,32)

    // staging role: thread = (g, p); g=3 (t>=243) inactive
    const int g     = t / 81;
    const int p     = t - g * 81;
    const bool stg  = (g < 3);
    const int wbase = p * RSTB + 8 * g;

    const float* xp[NOFF] = { x0, x1, x2, x3, x4, x5, x6, x7, x8 };

    // ---- B-fragment helpers ----
    // raw load for offset I: bwr[kt][of][0..1] = two aligned float4 from wts,
    // lane pattern: row o = 16*(2oh+of)+l15, cols 32kt+8lhi .. +7
    float4 bwr[2][2][2];
    bf16x8 bw[2][2];
#define LOADB(I)                                                                \
    _Pragma("unroll")                                                           \
    for (int _kt = 0; _kt < 2; ++_kt)                                           \
        _Pragma("unroll")                                                       \
        for (int _of = 0; _of < 2; ++_of) {                                     \
            const float* _wp = wts + (((I) * COUT + 16 * (oh * 2 + _of) + l15)  \
                                      * CIN + 32 * _kt + 8 * lhi);              \
            bwr[_kt][_of][0] = *(const float4*)_wp;                             \
            bwr[_kt][_of][1] = *(const float4*)(_wp + 4);                       \
        }
#define CVTB()                                                                  \
    _Pragma("unroll")                                                           \
    for (int _kt = 0; _kt < 2; ++_kt)                                           \
        _Pragma("unroll")                                                       \
        for (int _of = 0; _of < 2; ++_of) {                                     \
            int4 _ai;                                                           \
            _ai.x = f2bf(bwr[_kt][_of][0].x) | (f2bf(bwr[_kt][_of][0].y) << 16);\
            _ai.y = f2bf(bwr[_kt][_of][0].z) | (f2bf(bwr[_kt][_of][0].w) << 16);\
            _ai.z = f2bf(bwr[_kt][_of][1].x) | (f2bf(bwr[_kt][_of][1].y) << 16);\
            _ai.w = f2bf(bwr[_kt][_of][1].z) | (f2bf(bwr[_kt][_of][1].w) << 16);\
            bw[_kt][_of] = __builtin_bit_cast(bf16x8, _ai);                     \
        }

    // issue B loads for offset 0 first (L2), then the bulk x staging (HBM)
    LOADB(0)

    // ---- prologue: stage slab 0 -> buf 0 (load+cvt+write directly) ----
    if (stg) {
        const float* sp = xp[0] + (size_t)b * SLAB + g * 324 + p;
        unsigned char* wb = &xs[wbase];
#pragma unroll
        for (int k = 0; k < 5; ++k) {
            float c0 = sp[0], c1 = sp[81], c2 = sp[162], c3 = sp[243];
            uint2 v;
            v.x = f2bf(c0) | (f2bf(c1) << 16);
            v.y = f2bf(c2) | (f2bf(c3) << 16);
            *(uint2*)(wb + 24 * k) = v;
            sp += 972;
        }
        if (g == 0) {   // 16th quad (q=15)
            float c0 = sp[0], c1 = sp[81], c2 = sp[162], c3 = sp[243];
            uint2 v;
            v.x = f2bf(c0) | (f2bf(c1) << 16);
            v.y = f2bf(c2) | (f2bf(c3) << 16);
            *(uint2*)(wb + 120) = v;
        }
    }

    // ---- one-time: biasEff table into LDS (same sum order as old prep) ----
    for (int e = t; e < 9 * COUT; e += 256) {
        int w = e >> 6, o = e & 63;
        int lo = (w - 4 > 0) ? (w - 4) : 0;
        int hi = (w + 4 < 8) ? (w + 4) : 8;
        float s = 0.f;
        for (int i2 = lo; i2 <= hi; ++i2) s += bias[i2 * COUT + o];
        beff[e] = s;
    }

    // zero row ZR of both buffers (68 dwords)
    if (t < 68) {
        int idx = (t < 34) ? (ZR * RSTB + 4 * t)
                           : (BUFB + ZR * RSTB + 4 * (t - 34));
        *(unsigned int*)&xs[idx] = 0u;
    }

    __syncthreads();   // beff + zero rows + buf0 visible

    CVTB()             // bw ready for i=0 (loads long landed)

    // A-row constants (i-invariant)
    int pAv[3], wAv[3];
#pragma unroll
    for (int mt = 0; mt < 3; ++mt) {
        pAv[mt] = mh * 48 + mt * 16 + l15;
        wAv[mt] = pAv[mt] % 9;
    }

    // ---- acc init from LDS beff ----
    f32x4 acc[3][2];
#pragma unroll
    for (int mt = 0; mt < 3; ++mt) {
#pragma unroll
        for (int of = 0; of < 2; ++of) {
            const int ocol = oh * 32 + of * 16 + l15;
#pragma unroll
            for (int jj = 0; jj < 4; ++jj) {
                int pp = mh * 48 + mt * 16 + lhi * 4 + jj;
                if (pp > 80) pp = 80;                    // garbage rows (unstored)
                acc[mt][of][jj] = beff[(pp % 9) * COUT + ocol];
            }
        }
    }

#pragma unroll
    for (int i = 0; i < NOFF; ++i) {
        const unsigned char* bufR = &xs[(i & 1) * BUFB];

        // 1) issue x-stage loads for slab i+1 (HBM bulk — first)
        float sf[6][4];
        if (stg && i + 1 < NOFF) {
            const float* sp = xp[i + 1] + (size_t)b * SLAB + g * 324 + p;
#pragma unroll
            for (int k = 0; k < 5; ++k) {
                sf[k][0] = sp[0];   sf[k][1] = sp[81];
                sf[k][2] = sp[162]; sf[k][3] = sp[243];
                sp += 972;
            }
            if (g == 0) {
                sf[5][0] = sp[0];   sf[5][1] = sp[81];
                sf[5][2] = sp[162]; sf[5][3] = sp[243];
            }
        }

        // 2) issue B-fragment raw loads for offset i+1 (L2-hot)
        if (i + 1 < NOFF) { LOADB(i + 1) }

        // 3) A-frag reads (12 x ds_read_b64) + 12 MFMA (bw from LAST iter's cvt)
        const int d = i - 4;
#pragma unroll
        for (int mt = 0; mt < 3; ++mt) {
            const bool valid = (unsigned)(wAv[mt] - d) < 9u;
            const int q = valid ? (pAv[mt] - d) : ZR;     // row 81 = zeros
            const unsigned char* rp = bufR + q * RSTB + lhi * 16;

#pragma unroll
            for (int kt = 0; kt < 2; ++kt) {
                int2 lo = *(const int2*)(rp + kt * 64);
                int2 hi = *(const int2*)(rp + kt * 64 + 8);
                int4 ai = { lo.x, lo.y, hi.x, hi.y };
                bf16x8 af = __builtin_bit_cast(bf16x8, ai);

                acc[mt][0] = __builtin_amdgcn_mfma_f32_16x16x32_bf16(af, bw[kt][0], acc[mt][0], 0, 0, 0);
                acc[mt][1] = __builtin_amdgcn_mfma_f32_16x16x32_bf16(af, bw[kt][1], acc[mt][1], 0, 0, 0);
            }
        }

        // 4) cvt + ds_write slab i+1 into the other buffer; barrier
        if (i + 1 < NOFF) {
            if (stg) {
                unsigned char* wb = &xs[((i + 1) & 1) * BUFB + wbase];
#pragma unroll
                for (int k = 0; k < 5; ++k) {
                    uint2 v;
                    v.x = f2bf(sf[k][0]) | (f2bf(sf[k][1]) << 16);
                    v.y = f2bf(sf[k][2]) | (f2bf(sf[k][3]) << 16);
                    *(uint2*)(wb + 24 * k) = v;
                }
                if (g == 0) {
                    uint2 v;
                    v.x = f2bf(sf[5][0]) | (f2bf(sf[5][1]) << 16);
                    v.y = f2bf(sf[5][2]) | (f2bf(sf[5][3]) << 16);
                    *(uint2*)(wb + 120) = v;
                }
            }
            asm volatile("s_waitcnt lgkmcnt(0)" ::: "memory");
            __builtin_amdgcn_s_barrier();
            __builtin_amdgcn_sched_barrier(0);

            // 5) convert next iter's B fragments (off critical path; loads
            //    landed during the MFMA/DS phase)
            CVTB()
        }
    }

    // store: D row p' (natural h*9+w), col o
    float* ob = out + (size_t)b * COUT * HW;
#pragma unroll
    for (int mt = 0; mt < 3; ++mt) {
#pragma unroll
        for (int of = 0; of < 2; ++of) {
            const int ocol = oh * 32 + of * 16 + l15;
#pragma unroll
            for (int jj = 0; jj < 4; ++jj) {
                const int pp = mh * 48 + mt * 16 + lhi * 4 + jj;
                if (pp < 81) ob[ocol * HW + pp] = acc[mt][of][jj];
            }
        }
    }
#undef LOADB
#undef CVTB
}

extern "C" void kernel_launch(void* const* d_in, const int* in_sizes, int n_in,
                              void* d_out, int out_size, void* d_ws, size_t ws_size,
                              hipStream_t stream) {
    const float* x[9];
    for (int i = 0; i < 9; ++i) x[i] = (const float*)d_in[i];
    const float* wts  = (const float*)d_in[9];   // [9][64][64]
    const float* bias = (const float*)d_in[10];  // [9][64]
    float* out = (float*)d_out;

    // single dispatch: prep fully fused, workspace unused
    scatter_fused2_kernel<<<1024, 256, 0, stream>>>(
        x[0], x[1], x[2], x[3], x[4], x[5], x[6], x[7], x[8],
        wts, bias, out);
}

// Round 14
// 48.150 us; speedup vs baseline: 1.5346x; 1.5346x over previous
//
#include <hip/hip_runtime.h>
#include <hip/hip_bf16.h>

// ScatterHorizontal FINAL (= round 6 champion, 47.3 us): transpose-on-WRITE
// LDS layout [pixel][c], double-buffered bf16, reg-staged issue-early/
// write-late, 1 barrier/iter, 12 ds_read_b64 + 12 MFMA per thread per iter.
// Two dispatches: prep (wfrag bf16 B-fragments + biasEff) then main.
// Evidence ledger (R4-R13): five minimal-fetch structures all at 47-49 us;
// delivered ~212 MB at ~4.9 TB/s ~ 78% of copy ceiling; occupancy, prefetch
// depth, barrier coupling, DS width, zero-LDS streaming, dispatch fusion all
// ruled out as levers. This is the pattern roofline.
// out[b,o,h,w'] = sum_i [0<=w'-d_i<9]( sum_c W[i,o,c]*x_i[b,c,h,w'-d_i] + bias[i,o] )

#define CIN   64
#define COUT  64
#define NOFF  9
#define HW    81
#define SLAB  5184           // f32 per (b,i) slab
#define RSTB  136            // LDS row stride bytes (64 bf16 = 128 + 8 pad)
#define BUFB  (82 * RSTB)    // 11152 B per buffer (rows 0..80 data, row 81 zero)

typedef short bf16x8 __attribute__((ext_vector_type(8)));
typedef float f32x4  __attribute__((ext_vector_type(4)));

static __device__ __forceinline__ unsigned int f2bf(float v) {
    union { __hip_bfloat16 h; unsigned short u; } cv;
    cv.h = __float2bfloat16(v);
    return (unsigned int)cv.u;
}

// wfrag flat idx = (((i*2 + kt)*4 + ot)*64 + lane)*8 + j
//   value = bf16( W[i][o = 16*ot + (lane&15)][c = 32*kt + 8*(lane>>4) + j] )
__global__ __launch_bounds__(256) void prep_kernel(
    const float* __restrict__ wts,   // [9][64][64] (i,o,c)
    const float* __restrict__ bias,  // [9][64]
    unsigned short* __restrict__ wfrag,
    float* __restrict__ biasEff)     // [9][64] (w,o)
{
    int tid = blockIdx.x * 256 + threadIdx.x;
    int stride = gridDim.x * 256;
    for (int e = tid; e < NOFF * 4096; e += stride) {
        int j  = e & 7;
        int l  = (e >> 3) & 63;
        int ot = (e >> 9) & 3;
        int kt = (e >> 11) & 1;
        int i  = e >> 12;
        int o  = ot * 16 + (l & 15);
        int c  = kt * 32 + (l >> 4) * 8 + j;
        wfrag[e] = (unsigned short)f2bf(wts[(i * COUT + o) * CIN + c]);
    }
    if (blockIdx.x == 0) {
        for (int e = threadIdx.x; e < 9 * COUT; e += 256) {
            int w = e / COUT, o = e - w * COUT;
            int lo = (w - 4 > 0) ? (w - 4) : 0;
            int hi = (w + 4 < 8) ? (w + 4) : 8;
            float s = 0.f;
            for (int i2 = lo; i2 <= hi; ++i2) s += bias[i2 * COUT + o];
            biasEff[e] = s;
        }
    }
}

__global__ __launch_bounds__(256, 4) void scatter_mfma5_kernel(
    const float* __restrict__ x0, const float* __restrict__ x1,
    const float* __restrict__ x2, const float* __restrict__ x3,
    const float* __restrict__ x4, const float* __restrict__ x5,
    const float* __restrict__ x6, const float* __restrict__ x7,
    const float* __restrict__ x8,
    const unsigned short* __restrict__ wfrag,
    const float* __restrict__ biasEff,
    float* __restrict__ out)
{
    __shared__ __align__(16) unsigned char xs[2 * BUFB];   // 22304 B

    const int b    = blockIdx.x;
    const int t    = threadIdx.x;
    const int wid  = t >> 6;
    const int lane = t & 63;
    const int l15  = lane & 15;
    const int lhi  = lane >> 4;      // 0..3
    const int mh   = wid >> 1;       // m-half: rows mh*48 + [0,48)
    const int oh   = wid & 1;        // o-half: cols oh*32 + [0,32)

    // staging role: thread = (g, p); g=3 (t>=243) inactive
    const int g   = t / 81;
    const int p   = t - g * 81;
    const bool stg = (g < 3);
    const int wbase = p * RSTB + 8 * g;   // LDS byte base for this thread's writes

    const float* xp[NOFF] = { x0, x1, x2, x3, x4, x5, x6, x7, x8 };

    // A-row constants (i-invariant)
    int pAv[3], wAv[3];
#pragma unroll
    for (int mt = 0; mt < 3; ++mt) {
        pAv[mt] = mh * 48 + mt * 16 + l15;
        wAv[mt] = pAv[mt] % 9;
    }

    // accumulators init = biasEff[w'][o]
    f32x4 acc[3][2];
#pragma unroll
    for (int mt = 0; mt < 3; ++mt) {
#pragma unroll
        for (int of = 0; of < 2; ++of) {
            const int ocol = oh * 32 + of * 16 + l15;
#pragma unroll
            for (int jj = 0; jj < 4; ++jj) {
                int pp = mh * 48 + mt * 16 + lhi * 4 + jj;
                if (pp > 80) pp = 80;                    // garbage rows (unstored)
                acc[mt][of][jj] = biasEff[(pp % 9) * COUT + ocol];
            }
        }
    }

    // zero row 81 of both buffers (68 dwords total)
    if (t < 68) {
        int idx = (t < 34) ? (81 * RSTB + 4 * t)
                           : (BUFB + 81 * RSTB + 4 * (t - 34));
        *(unsigned int*)&xs[idx] = 0u;
    }

    // ---- prologue: stage slab 0 -> buf 0 (load+cvt+write directly) ----
    if (stg) {
        const float* sp = xp[0] + (size_t)b * SLAB + g * 324 + p;
        unsigned char* wb = &xs[wbase];
#pragma unroll
        for (int k = 0; k < 5; ++k) {
            float f0 = sp[0], f1 = sp[81], f2 = sp[162], f3 = sp[243];
            uint2 v;
            v.x = f2bf(f0) | (f2bf(f1) << 16);
            v.y = f2bf(f2) | (f2bf(f3) << 16);
            *(uint2*)(wb + 24 * k) = v;
            sp += 972;
        }
        if (g == 0) {   // 16th quad (q=15)
            float f0 = sp[0], f1 = sp[81], f2 = sp[162], f3 = sp[243];
            uint2 v;
            v.x = f2bf(f0) | (f2bf(f1) << 16);
            v.y = f2bf(f2) | (f2bf(f3) << 16);
            *(uint2*)(wb + 120) = v;
        }
    }
    asm volatile("s_waitcnt lgkmcnt(0)" ::: "memory");
    __builtin_amdgcn_s_barrier();
    __builtin_amdgcn_sched_barrier(0);

#pragma unroll
    for (int i = 0; i < NOFF; ++i) {
        const unsigned char* bufR = &xs[(i & 1) * BUFB];

        // 1) B fragments for this offset (vector loads; wfrag L2-hot)
        bf16x8 bw[2][2];
#pragma unroll
        for (int kt = 0; kt < 2; ++kt)
#pragma unroll
            for (int of = 0; of < 2; ++of) {
                const int ot = oh * 2 + of;
                bw[kt][of] = *(const bf16x8*)&wfrag[(((i * 2 + kt) * 4 + ot) * 64 + lane) * 8];
            }

        // 2) issue stage loads for slab i+1 (latency hides under DS+MFMA phase)
        float sf[6][4];
        if (stg && i + 1 < NOFF) {
            const float* sp = xp[i + 1] + (size_t)b * SLAB + g * 324 + p;
#pragma unroll
            for (int k = 0; k < 5; ++k) {
                sf[k][0] = sp[0]; sf[k][1] = sp[81];
                sf[k][2] = sp[162]; sf[k][3] = sp[243];
                sp += 972;
            }
            if (g == 0) {
                sf[5][0] = sp[0]; sf[5][1] = sp[81];
                sf[5][2] = sp[162]; sf[5][3] = sp[243];
            }
        }

        // 3) A-frag reads (12 x ds_read_b64) + 12 MFMA
        const int d = i - 4;
#pragma unroll
        for (int mt = 0; mt < 3; ++mt) {
            const bool valid = (unsigned)(wAv[mt] - d) < 9u;
            const int q = valid ? (pAv[mt] - d) : 81;     // row 81 = zeros
            const unsigned char* rp = bufR + q * RSTB + lhi * 16;

#pragma unroll
            for (int kt = 0; kt < 2; ++kt) {
                int2 lo = *(const int2*)(rp + kt * 64);
                int2 hi = *(const int2*)(rp + kt * 64 + 8);
                int4 ai = { lo.x, lo.y, hi.x, hi.y };
                bf16x8 af = __builtin_bit_cast(bf16x8, ai);

                acc[mt][0] = __builtin_amdgcn_mfma_f32_16x16x32_bf16(af, bw[kt][0], acc[mt][0], 0, 0, 0);
                acc[mt][1] = __builtin_amdgcn_mfma_f32_16x16x32_bf16(af, bw[kt][1], acc[mt][1], 0, 0, 0);
            }
        }

        // 4) cvt + ds_write slab i+1 into the other buffer; 5) barrier
        if (i + 1 < NOFF) {
            if (stg) {
                unsigned char* wb = &xs[((i + 1) & 1) * BUFB + wbase];
#pragma unroll
                for (int k = 0; k < 5; ++k) {
                    uint2 v;
                    v.x = f2bf(sf[k][0]) | (f2bf(sf[k][1]) << 16);
                    v.y = f2bf(sf[k][2]) | (f2bf(sf[k][3]) << 16);
                    *(uint2*)(wb + 24 * k) = v;
                }
                if (g == 0) {
                    uint2 v;
                    v.x = f2bf(sf[5][0]) | (f2bf(sf[5][1]) << 16);
                    v.y = f2bf(sf[5][2]) | (f2bf(sf[5][3]) << 16);
                    *(uint2*)(wb + 120) = v;
                }
            }
            asm volatile("s_waitcnt lgkmcnt(0)" ::: "memory");
            __builtin_amdgcn_s_barrier();
            __builtin_amdgcn_sched_barrier(0);
        }
    }

    // store: D row p' (natural h*9+w), col o
    float* ob = out + (size_t)b * COUT * HW;
#pragma unroll
    for (int mt = 0; mt < 3; ++mt) {
#pragma unroll
        for (int of = 0; of < 2; ++of) {
            const int ocol = oh * 32 + of * 16 + l15;
#pragma unroll
            for (int jj = 0; jj < 4; ++jj) {
                const int pp = mh * 48 + mt * 16 + lhi * 4 + jj;
                if (pp < 81) ob[ocol * HW + pp] = acc[mt][of][jj];
            }
        }
    }
}

extern "C" void kernel_launch(void* const* d_in, const int* in_sizes, int n_in,
                              void* d_out, int out_size, void* d_ws, size_t ws_size,
                              hipStream_t stream) {
    const float* x[9];
    for (int i = 0; i < 9; ++i) x[i] = (const float*)d_in[i];
    const float* wts  = (const float*)d_in[9];
    const float* bias = (const float*)d_in[10];
    float* out = (float*)d_out;

    unsigned short* wfrag = (unsigned short*)d_ws;                    // 73728 B
    float* biasEff = (float*)((char*)d_ws + NOFF * 4096 * sizeof(unsigned short));

    prep_kernel<<<144, 256, 0, stream>>>(wts, bias, wfrag, biasEff);
    scatter_mfma5_kernel<<<1024, 256, 0, stream>>>(
        x[0], x[1], x[2], x[3], x[4], x[5], x[6], x[7], x[8],
        wfrag, biasEff, out);
}